// Round 8
// baseline (491.922 us; speedup 1.0000x reference)
//
#include <hip/hip_runtime.h>

#define TT 512
#define DD 16
#define HH 48
#define BT 4       // batch rows per block -> 512 blocks, 2/CU: two independent barrier domains
#define NTHR 384   // 6 waves; each wave owns TWO 16-row M-tiles; every lane owns ONE unique cell
#define CHUNK 64   // timesteps of x resident in LDS ring

// LDS (ushort units):
//  [0, 8192)      x-ring: 64 tiles x 128 (tile = 2 kgrp x 64; cols 0-3 = batch, 4-7 = zero)
//  [8192, 9728)   B dbuf: 2 parities x 12 kgrp x 64. Col n (0-7): n<4 -> L0 input batch n
//                 [x k0-15 (unused here, lives in ring) | h1prev k16-63 | zero k64-95];
//                 n>=4 -> L1 input batch n-4 [h1 k0-47 | h2prev k48-95].
//                 MFMA cols 8-15 mirror 0-7 via read addressing (same-addr broadcast, free).
#define XB 8192
#define STOT 9728

typedef short bf8v __attribute__((ext_vector_type(8)));   // 8 x bf16 bits
typedef float f32x4 __attribute__((ext_vector_type(4)));

__device__ __forceinline__ ushort bfb(float f) {
    return __builtin_bit_cast(ushort, (__bf16)f);
}

// y = A*rcp(1+exp2(M*x)) + B  (sigmoid: A=1,M=-log2e,B=0; tanh: A=2,M=-2log2e,B=-1)
__device__ __forceinline__ float actf(float x, float A, float M, float Bc) {
    float e = __builtin_amdgcn_exp2f(M * x);
    return __builtin_fmaf(A, __builtin_amdgcn_rcpf(1.0f + e), Bc);
}

// LDS-only barrier (no global ops in flight across bodies)
__device__ __forceinline__ void barrier_lds() {
    asm volatile("s_waitcnt lgkmcnt(0)\ns_barrier" ::: "memory");
}

__global__ __launch_bounds__(NTHR)
void lstm_kernel(const float* __restrict__ x,
                 const float* __restrict__ Wih0, const float* __restrict__ Whh0,
                 const float* __restrict__ bih0, const float* __restrict__ bhh0,
                 const float* __restrict__ Wih1, const float* __restrict__ Whh1,
                 const float* __restrict__ bih1, const float* __restrict__ bhh1,
                 const float* __restrict__ fcw, const float* __restrict__ fcb,
                 float* __restrict__ out)
{
    __shared__ alignas(16) ushort S[STOT];
    __shared__ float outl[BT][HH];

    const int tid  = threadIdx.x;
    const int lane = tid & 63;
    const int wave = tid >> 6;            // 0..5
    const int b0   = blockIdx.x * BT;

    const int colq = lane & 15;
    const int quad = lane >> 4;
    const int bcol = colq & 3;            // batch 0..3
    const int isL1 = (colq >> 2) & 1;     // cols 4-7,12-15: L1 cell
    const int u    = 8 * wave + ((colq & 8) ? 4 : 0) + quad;   // this lane's cell unit
    const int uA   = 8 * wave + quad;     // tile-A unit (C/D rows)
    const int uB   = uA + 4;              // tile-B unit

    const float L2E = 1.4426950408889634f;

    // ---- loop-invariant LDS offsets (ushort units) ----
    const int fb = (colq & 7) * 8;                 // cols 8-15 mirror 0-7
    const int GE = XB + quad * 64 + fb;            // g0 base, parity 0 (g1=+256, g2=+512; a1==g1)
    const int GO = GE + 768;                       // parity 1
    const int inc = (quad < 2) ? 256 : 0;          // x-ring advance per body-pair (quads 0-1 only)
    // h writes (offsets within one parity block):
    const int o1 = ((16 + u) >> 3) * 64 + bcol * 8 + ((16 + u) & 7);        // h1 -> h1prev slot
    const int o2 = (u >> 3) * 64 + (4 + bcol) * 8 + (u & 7);                // h1 -> L1-input slot
    const int o3 = ((48 + u) >> 3) * 64 + (4 + bcol) * 8 + ((48 + u) & 7);  // h2 -> h2prev slot

    // ---- C-operand biases: acc reg r = gate type r of unit uA/uB ----
    f32x4 b0A, b1A, b0B, b1B;
#pragma unroll
    for (int r = 0; r < 4; ++r) {
        b0A[r] = bih0[r * 48 + uA] + bhh0[r * 48 + uA];
        b1A[r] = bih1[r * 48 + uA] + bhh1[r * 48 + uA];
        b0B[r] = bih0[r * 48 + uB] + bhh0[r * 48 + uB];
        b1B[r] = bih1[r * 48 + uB] + bhh1[r * 48 + uB];
    }

    // ---- step-invariant weight A-fragments (2 tiles x (2 L0 + 3 L1) = 10 frags) ----
    // A-frag: lane holds A[m=colq][k=quad*8+j]; tile t row m -> PyTorch gate index:
    const int giA = (colq & 3) * 48 + 8 * wave + (colq >> 2);
    const int giB = giA + 4;
    bf8v wA0f0, wA0f1, wA1f0, wA1f1, wA1f2;
    bf8v wB0f0, wB0f1, wB1f0, wB1f1, wB1f2;
    {
        auto l0 = [&](int gi, bf8v& f0, bf8v& f1) {
            bf8v w;
#pragma unroll
            for (int j = 0; j < 8; ++j) {          // k 0..31
                int k = quad * 8 + j;
                float v = (k < 16) ? Wih0[gi * 16 + k] : Whh0[gi * 48 + (k - 16)];
                w[j] = (short)bfb(v);
            }
            f0 = w;
#pragma unroll
            for (int j = 0; j < 8; ++j) {          // k 32..63 -> Whh0
                int k = 32 + quad * 8 + j;
                w[j] = (short)bfb(Whh0[gi * 48 + (k - 16)]);
            }
            f1 = w;
        };
        auto l1 = [&](int gi, bf8v& f0, bf8v& f1, bf8v& f2) {
            bf8v w;
#pragma unroll
            for (int j = 0; j < 8; ++j) {          // k 0..31 -> Wih1
                int k = quad * 8 + j;
                w[j] = (short)bfb(Wih1[gi * 48 + k]);
            }
            f0 = w;
#pragma unroll
            for (int j = 0; j < 8; ++j) {          // k 32..63
                int k = 32 + quad * 8 + j;
                float v = (k < 48) ? Wih1[gi * 48 + k] : Whh1[gi * 48 + (k - 48)];
                w[j] = (short)bfb(v);
            }
            f1 = w;
#pragma unroll
            for (int j = 0; j < 8; ++j) {          // k 64..95 -> Whh1
                int k = 64 + quad * 8 + j;
                w[j] = (short)bfb(Whh1[gi * 48 + (k - 48)]);
            }
            f2 = w;
        };
        l0(giA, wA0f0, wA0f1);  l1(giA, wA1f0, wA1f1, wA1f2);
        l0(giB, wB0f0, wB0f1);  l1(giB, wB1f0, wB1f1, wB1f2);
    }

    // ---- init: zero all of S (h1prev, h2prev, static-zero regions, ring cols 4-7) ----
    {
        uint* p = (uint*)S;
        for (int i = tid; i < STOT / 2; i += NTHR) p[i] = 0;
    }
    __syncthreads();

    float c = 0.f;     // L0 lanes: c0; L1 lanes: c1
    float hv = 0.f;

#define MFMA(A, B, C) __builtin_amdgcn_mfma_f32_16x16x32_bf16(A, B, C, 0, 0, 0)

    // body t: L0(t) [tiles A,B] + L1(t-1) [tiles A,B]; reads B[p]+ring, writes B[p^1]; 1 barrier
#define BODY(A0OFF, G0OFF, WBASE, DOL1) { \
        bf8v a0 = *(const bf8v*)&S[A0OFF]; \
        bf8v g0 = *(const bf8v*)&S[G0OFF]; \
        bf8v g1 = *(const bf8v*)&S[(G0OFF) + 256]; \
        bf8v g2 = *(const bf8v*)&S[(G0OFF) + 512]; \
        f32x4 a0A = MFMA(wA0f0, a0, b0A);  a0A = MFMA(wA0f1, g1, a0A); \
        f32x4 a0B = MFMA(wB0f0, a0, b0B);  a0B = MFMA(wB0f1, g1, a0B); \
        f32x4 sL0, pre; \
        sL0[0] = (colq & 8) ? a0B[0] : a0A[0]; \
        sL0[1] = (colq & 8) ? a0B[1] : a0A[1]; \
        sL0[2] = (colq & 8) ? a0B[2] : a0A[2]; \
        sL0[3] = (colq & 8) ? a0B[3] : a0A[3]; \
        if (DOL1) { \
            f32x4 a1A = MFMA(wA1f0, g0, b1A); \
            a1A = MFMA(wA1f1, g1, a1A);  a1A = MFMA(wA1f2, g2, a1A); \
            f32x4 a1B = MFMA(wB1f0, g0, b1B); \
            a1B = MFMA(wB1f1, g1, a1B);  a1B = MFMA(wB1f2, g2, a1B); \
            f32x4 sL1; \
            sL1[0] = (colq & 8) ? a1B[0] : a1A[0]; \
            sL1[1] = (colq & 8) ? a1B[1] : a1A[1]; \
            sL1[2] = (colq & 8) ? a1B[2] : a1A[2]; \
            sL1[3] = (colq & 8) ? a1B[3] : a1A[3]; \
            pre[0] = isL1 ? sL1[0] : sL0[0]; \
            pre[1] = isL1 ? sL1[1] : sL0[1]; \
            pre[2] = isL1 ? sL1[2] : sL0[2]; \
            pre[3] = isL1 ? sL1[3] : sL0[3]; \
        } else { \
            pre = sL0; \
        } \
        float iv = actf(pre[0], 1.0f, -L2E, 0.0f); \
        float fv = actf(pre[1], 1.0f, -L2E, 0.0f); \
        float gv = actf(pre[2], 2.0f, -2.0f * L2E, -1.0f); \
        float ov = actf(pre[3], 1.0f, -L2E, 0.0f); \
        float cn = __builtin_fmaf(fv, c, iv * gv); \
        if (!DOL1) cn = isL1 ? c : cn;   /* peel: keep L1 state at 0 */ \
        c = cn; \
        float tc = actf(cn, 2.0f, -2.0f * L2E, -1.0f); \
        hv = ov * tc; \
        ushort hb = bfb(hv); \
        if (!isL1) { S[(WBASE) + o1] = hb; S[(WBASE) + o2] = hb; } \
        else if (DOL1) { S[(WBASE) + o3] = hb; } \
        barrier_lds(); \
    }

    for (int ck = 0; ck < TT / CHUNK; ++ck) {
        // ---- refill x ring for t in [ck*64, ck*64+64): coalesced float4, all waves ----
        for (int i = tid; i < BT * CHUNK * 4; i += NTHR) {   // 1024 float4 rows
            int g  = i & 3;
            int tl = (i >> 2) & (CHUNK - 1);
            int b  = i >> 8;
            const float4 v = *(const float4*)(x +
                ((size_t)(b0 + b) * TT + (ck * CHUNK + tl)) * DD + g * 4);
            ushort4 s4;
            s4.x = bfb(v.x); s4.y = bfb(v.y); s4.z = bfb(v.z); s4.w = bfb(v.w);
            *(ushort4*)&S[tl * 128 + (g >> 1) * 64 + b * 8 + (g & 1) * 4] = s4;
        }
        __syncthreads();   // full drain; all loads are within this chunk's refill

        // a0 mixed addresses: quads 0-1 -> x ring (tile j), quads 2-3 -> B[p] kgrp 2-3
        int aE = (quad < 2) ? (quad * 64 + fb) : (XB + quad * 64 + fb);
        int aO = (quad < 2) ? (128 + quad * 64 + fb) : (XB + 768 + quad * 64 + fb);

        int p0 = 0;
        if (ck == 0) {   // peel: first body has no L1 yet
            BODY(aE, GE, XB + 768, false)
            BODY(aO, GO, XB, true)
            aE += inc; aO += inc;
            p0 = 1;
        }
        for (int p = p0; p < CHUNK / 2; ++p) {
            BODY(aE, GE, XB + 768, true)
            BODY(aO, GO, XB, true)
            aE += inc; aO += inc;
        }
    }

    // ---- post-peel: L1(511) from B[0] (t=511 wrote parity 0) ----
    {
        bf8v g0 = *(const bf8v*)&S[GE];
        bf8v g1 = *(const bf8v*)&S[GE + 256];
        bf8v g2 = *(const bf8v*)&S[GE + 512];
        f32x4 a1A = MFMA(wA1f0, g0, b1A);
        a1A = MFMA(wA1f1, g1, a1A);  a1A = MFMA(wA1f2, g2, a1A);
        f32x4 a1B = MFMA(wB1f0, g0, b1B);
        a1B = MFMA(wB1f1, g1, a1B);  a1B = MFMA(wB1f2, g2, a1B);
        f32x4 sL1;
        sL1[0] = (colq & 8) ? a1B[0] : a1A[0];
        sL1[1] = (colq & 8) ? a1B[1] : a1A[1];
        sL1[2] = (colq & 8) ? a1B[2] : a1A[2];
        sL1[3] = (colq & 8) ? a1B[3] : a1A[3];
        float iv = actf(sL1[0], 1.0f, -L2E, 0.0f);
        float fv = actf(sL1[1], 1.0f, -L2E, 0.0f);
        float gv = actf(sL1[2], 2.0f, -2.0f * L2E, -1.0f);
        float ov = actf(sL1[3], 1.0f, -L2E, 0.0f);
        float cn = __builtin_fmaf(fv, c, iv * gv);
        float tc = actf(cn, 2.0f, -2.0f * L2E, -1.0f);
        hv = ov * tc;                       // valid in L1 lanes: h2(511) for (bcol, u)
    }

    if (isL1) outl[bcol][u] = hv;
    __syncthreads();
    if (tid < BT) {
        float s = fcb[0];
        for (int uu = 0; uu < HH; ++uu) s = __builtin_fmaf(outl[tid][uu], fcw[uu], s);
        out[b0 + tid] = actf(s, 1.0f, -L2E, 0.0f);
    }
#undef BODY
#undef MFMA
}

extern "C" void kernel_launch(void* const* d_in, const int* in_sizes, int n_in,
                              void* d_out, int out_size, void* d_ws, size_t ws_size,
                              hipStream_t stream) {
    const float* x    = (const float*)d_in[0];
    const float* Wih0 = (const float*)d_in[1];
    const float* Whh0 = (const float*)d_in[2];
    const float* bih0 = (const float*)d_in[3];
    const float* bhh0 = (const float*)d_in[4];
    const float* Wih1 = (const float*)d_in[5];
    const float* Whh1 = (const float*)d_in[6];
    const float* bih1 = (const float*)d_in[7];
    const float* bhh1 = (const float*)d_in[8];
    const float* fcw  = (const float*)d_in[9];
    const float* fcb  = (const float*)d_in[10];
    lstm_kernel<<<2048 / BT, NTHR, 0, stream>>>(x, Wih0, Whh0, bih0, bhh0,
                                                Wih1, Whh1, bih1, bhh1, fcw, fcb,
                                                (float*)d_out);
}

// Round 9
// 295.302 us; speedup vs baseline: 1.6658x; 1.6658x over previous
//
#include <hip/hip_runtime.h>

#define TT 512
#define DD 16
#define HH 48
#define BT 8       // batch rows per block -> 256 blocks, one per CU (the schedulable optimum)
#define NTHR 768   // 12 waves; every lane owns exactly one cell (8b x 48u x 2 layers)
#define CHUNK 64   // timesteps of x resident in LDS ring

// LDS (ushort units):
//  [0, 8192)       x-ring: 64 tiles x 128 (tile = 2 kgrp x 8 cols x 8)
//  [8192, 9728)    B dbuf: 2 parities x 12 kgrp x 64 (8 physical cols = batch).
//    K-space (L0, re-permuted weights): k0-47 h1prev | k48-63 x (x read from ring, not stored)
//    K-space (L1):                      k0-47 h1     | k48-95 h2prev
//    k0-47 is SHARED (h1) -> one write, mirror-read serves both layers' MFMA cols.
#define XB 8192
#define STOT (XB + 1536)

typedef short bf8v __attribute__((ext_vector_type(8)));   // 8 x bf16 bits
typedef float f32x4 __attribute__((ext_vector_type(4)));

__device__ __forceinline__ ushort bfb(float f) {
    return __builtin_bit_cast(ushort, (__bf16)f);
}

// y = A*rcp(1+exp2(M*x)) + B  (sigmoid: A=1,M=-log2e,B=0; tanh: A=2,M=-2log2e,B=-1)
__device__ __forceinline__ float actf(float x, float A, float M, float Bc) {
    float e = __builtin_amdgcn_exp2f(M * x);
    return __builtin_fmaf(A, __builtin_amdgcn_rcpf(1.0f + e), Bc);
}

// LDS-only barrier (no global ops in flight across bodies; refill drains via __syncthreads)
__device__ __forceinline__ void barrier_lds() {
    asm volatile("s_waitcnt lgkmcnt(0)\ns_barrier" ::: "memory");
}

__global__ __launch_bounds__(NTHR)
void lstm_kernel(const float* __restrict__ x,
                 const float* __restrict__ Wih0, const float* __restrict__ Whh0,
                 const float* __restrict__ bih0, const float* __restrict__ bhh0,
                 const float* __restrict__ Wih1, const float* __restrict__ Whh1,
                 const float* __restrict__ bih1, const float* __restrict__ bhh1,
                 const float* __restrict__ fcw, const float* __restrict__ fcb,
                 float* __restrict__ out)
{
    __shared__ alignas(16) ushort S[STOT];
    __shared__ float outl[BT][HH];

    const int tid  = threadIdx.x;
    const int lane = tid & 63;
    const int wave = tid >> 6;
    const int b0   = blockIdx.x * BT;

    const int colq = lane & 15;
    const int quad = lane >> 4;
    const int b    = colq & 7;            // physical batch col
    const bool hi  = (colq >= 8);         // hi: L1 cell; lo: L0 cell (both batch b)
    const int u    = wave * 4 + quad;     // unit owned in C/D: acc[r] = gate r of unit u

    const float L2E = 1.4426950408889634f;

    // ---- loop-invariant LDS addresses (ushort units) ----
    const int fbm = b * 8;                          // mirror col base (cols 8-15 alias 0-7)
    const bool ringlane = (quad >= 2) && !hi;       // r1 lanes that read x from the ring
    const int r0E = XB + quad * 64 + fbm;           // k0-31  (h1, mirror-broadcast)
    const int r0O = r0E + 768;
    const int r2E = XB + (8 + quad) * 64 + fbm;     // k64-95 (h2prev u16-47, mirror)
    const int r2O = r2E + 768;
    const int r1statE = XB + (4 + quad) * 64 + fbm; // k32-63 static part (h1 u32-47 / h2prev u0-15)
    const int r1statO = r1statE + 768;
    const int r1ring0 = (quad - 2) * 64 + colq * 8; // k48-63 = x, ring tile 0 base
    const int inc = ringlane ? 256 : 0;             // ring advance per body pair
    const int kk = hi ? 48 + u : u;                 // write: lo h1 (k=u), hi h2 (k=48+u)
    const int woff = (kk >> 3) * 64 + b * 8 + (kk & 7);
    const int wE = XB + 768 + woff;                 // parity-0 body writes parity 1
    const int wO = XB + woff;

    // ---- C-operand biases: acc reg r = gate type r of unit u ----
    f32x4 bias0, bias1;
#pragma unroll
    for (int r = 0; r < 4; ++r) {
        bias0[r] = bih0[r * 48 + u] + bhh0[r * 48 + u];
        bias1[r] = bih1[r * 48 + u] + bhh1[r * 48 + u];
    }

    // ---- step-invariant weight A-fragments (K re-permuted for L0) ----
    // A-frag: lane holds A[m=colq][k=quad*8+j]; interleaved gate row -> PyTorch gi:
    const int gi = (colq & 3) * 48 + wave * 4 + (colq >> 2);
    bf8v w0k0, w0k1, w1k0, w1k1, w1k2;
    {
        bf8v w;
#pragma unroll
        for (int j = 0; j < 8; ++j) {     // L0 k0-31 -> Whh0 (h1prev)
            int k = quad * 8 + j;
            w[j] = (short)bfb(Whh0[gi * 48 + k]);
        }
        w0k0 = w;
#pragma unroll
        for (int j = 0; j < 8; ++j) {     // L0 k32-63: k<48 Whh0, else Wih0 (x)
            int k = 32 + quad * 8 + j;
            float v = (k < 48) ? Whh0[gi * 48 + k] : Wih0[gi * 16 + (k - 48)];
            w[j] = (short)bfb(v);
        }
        w0k1 = w;
#pragma unroll
        for (int j = 0; j < 8; ++j) {     // L1 k0-31 -> Wih1 (h1)
            int k = quad * 8 + j;
            w[j] = (short)bfb(Wih1[gi * 48 + k]);
        }
        w1k0 = w;
#pragma unroll
        for (int j = 0; j < 8; ++j) {     // L1 k32-63: k<48 Wih1, else Whh1 (h2prev)
            int k = 32 + quad * 8 + j;
            float v = (k < 48) ? Wih1[gi * 48 + k] : Whh1[gi * 48 + (k - 48)];
            w[j] = (short)bfb(v);
        }
        w1k1 = w;
#pragma unroll
        for (int j = 0; j < 8; ++j) {     // L1 k64-95 -> Whh1 (h2prev u16-47)
            int k = 64 + quad * 8 + j;
            w[j] = (short)bfb(Whh1[gi * 48 + (k - 48)]);
        }
        w1k2 = w;
    }

    // ---- init: zero all of S (h1/h2prev start at 0; junk cols bounded) ----
    {
        uint* p = (uint*)S;
        for (int i = tid; i < STOT / 2; i += NTHR) p[i] = 0;
    }
    __syncthreads();

    float c = 0.f;     // lo: c0; hi: c1
    float hv = 0.f;

#define MFMA(A, B, C) __builtin_amdgcn_mfma_f32_16x16x32_bf16(A, B, C, 0, 0, 0)

    // body t: L0(t) + L1(t-1); 3 ds_read_b128, 5 MFMA, 1 cell, 1 ds_write_b16, 1 barrier
#define BODY(V0A, V1A, V2A, WA, DOL1) { \
        bf8v v0 = *(const bf8v*)&S[V0A]; \
        bf8v v1 = *(const bf8v*)&S[V1A]; \
        bf8v v2 = *(const bf8v*)&S[V2A]; \
        f32x4 acc0 = MFMA(w0k0, v0, bias0); \
        acc0 = MFMA(w0k1, v1, acc0); \
        f32x4 pre; \
        if (DOL1) { \
            f32x4 acc1 = MFMA(w1k0, v0, bias1); \
            acc1 = MFMA(w1k1, v1, acc1); \
            acc1 = MFMA(w1k2, v2, acc1); \
            pre[0] = hi ? acc1[0] : acc0[0]; \
            pre[1] = hi ? acc1[1] : acc0[1]; \
            pre[2] = hi ? acc1[2] : acc0[2]; \
            pre[3] = hi ? acc1[3] : acc0[3]; \
        } else { \
            pre = acc0; \
        } \
        float iv = actf(pre[0], 1.0f, -L2E, 0.0f); \
        float fv = actf(pre[1], 1.0f, -L2E, 0.0f); \
        float gv = actf(pre[2], 2.0f, -2.0f * L2E, -1.0f); \
        float ov = actf(pre[3], 1.0f, -L2E, 0.0f); \
        float cn = __builtin_fmaf(fv, c, iv * gv); \
        if (!DOL1) cn = hi ? c : cn;   /* peel: keep L1 state at 0 */ \
        c = cn; \
        float tc = actf(cn, 2.0f, -2.0f * L2E, -1.0f); \
        hv = ov * tc; \
        ushort hb = bfb(hv); \
        if (!hi) { S[WA] = hb; } \
        else if (DOL1) { S[WA] = hb; } \
        barrier_lds(); \
    }

    for (int ck = 0; ck < TT / CHUNK; ++ck) {
        // ---- refill x ring for t in [ck*64, ck*64+64): coalesced float4, all waves ----
        for (int i = tid; i < BT * CHUNK * 4; i += NTHR) {   // 2048 float4 rows
            int g  = i & 3;
            int tl = (i >> 2) & (CHUNK - 1);
            int bb = i >> 8;
            const float4 v = *(const float4*)(x +
                ((size_t)(b0 + bb) * TT + (ck * CHUNK + tl)) * DD + g * 4);
            ushort4 s4;
            s4.x = bfb(v.x); s4.y = bfb(v.y); s4.z = bfb(v.z); s4.w = bfb(v.w);
            *(ushort4*)&S[tl * 128 + (g >> 1) * 64 + bb * 8 + (g & 1) * 4] = s4;
        }
        __syncthreads();   // full drain; all global loads are within this refill

        // r1 per-chunk: ring lanes restart at tile 0/1, others static per parity
        int r1E = ringlane ? r1ring0 : r1statE;
        int r1O = ringlane ? (128 + r1ring0) : r1statO;

        int p0 = 0;
        if (ck == 0) {   // peel: first body has no L1 yet
            BODY(r0E, r1E, r2E, wE, false)
            BODY(r0O, r1O, r2O, wO, true)
            r1E += inc; r1O += inc;
            p0 = 1;
        }
        for (int p = p0; p < CHUNK / 2; ++p) {
            BODY(r0E, r1E, r2E, wE, true)
            BODY(r0O, r1O, r2O, wO, true)
            r1E += inc; r1O += inc;
        }
    }

    // ---- post-peel: L1(511) from parity 0 (body 511 wrote h1(511), h2(510) there).
    // Ring lanes' r1 cols are junk for L1 (cols 0-7 unused by acc1) — bounded, in-range.
    {
        int r1E = ringlane ? (r1ring0 + 32 * 256) : r1statE;   // in-bounds junk for ring lanes
        bf8v v0 = *(const bf8v*)&S[r0E];
        bf8v v1 = *(const bf8v*)&S[r1E];
        bf8v v2 = *(const bf8v*)&S[r2E];
        f32x4 acc1 = MFMA(w1k0, v0, bias1);
        acc1 = MFMA(w1k1, v1, acc1);
        acc1 = MFMA(w1k2, v2, acc1);
        float iv = actf(acc1[0], 1.0f, -L2E, 0.0f);
        float fv = actf(acc1[1], 1.0f, -L2E, 0.0f);
        float gv = actf(acc1[2], 2.0f, -2.0f * L2E, -1.0f);
        float ov = actf(acc1[3], 1.0f, -L2E, 0.0f);
        float cn = __builtin_fmaf(fv, c, iv * gv);
        float tc = actf(cn, 2.0f, -2.0f * L2E, -1.0f);
        hv = ov * tc;                       // valid in hi lanes: h2(511) for (b, u)
    }

    // epilogue: hi lanes own (batch=b, unit=u) of h2(T-1)
    if (hi) outl[b][u] = hv;
    __syncthreads();
    if (tid < BT) {
        float s = fcb[0];
        for (int uu = 0; uu < HH; ++uu) s = __builtin_fmaf(outl[tid][uu], fcw[uu], s);
        out[b0 + tid] = actf(s, 1.0f, -L2E, 0.0f);
    }
#undef BODY
#undef MFMA
}

extern "C" void kernel_launch(void* const* d_in, const int* in_sizes, int n_in,
                              void* d_out, int out_size, void* d_ws, size_t ws_size,
                              hipStream_t stream) {
    const float* x    = (const float*)d_in[0];
    const float* Wih0 = (const float*)d_in[1];
    const float* Whh0 = (const float*)d_in[2];
    const float* bih0 = (const float*)d_in[3];
    const float* bhh0 = (const float*)d_in[4];
    const float* Wih1 = (const float*)d_in[5];
    const float* Whh1 = (const float*)d_in[6];
    const float* bih1 = (const float*)d_in[7];
    const float* bhh1 = (const float*)d_in[8];
    const float* fcw  = (const float*)d_in[9];
    const float* fcb  = (const float*)d_in[10];
    lstm_kernel<<<2048 / BT, NTHR, 0, stream>>>(x, Wih0, Whh0, bih0, bhh0,
                                                Wih1, Whh1, bih1, bhh1, fcw, fcb,
                                                (float*)d_out);
}

// Round 10
// 280.407 us; speedup vs baseline: 1.7543x; 1.0531x over previous
//
#include <hip/hip_runtime.h>

#define TT 512
#define DD 16
#define HH 48
#define BT 8       // batch rows per block -> 256 blocks, one per CU (the schedulable optimum)
#define NTHR 768   // 12 waves; every lane owns exactly one cell (8b x 48u x 2 layers)
#define CHUNK 64   // timesteps of x resident in LDS ring

// LDS (ushort units):
//  [0, 8192)       x-ring: 64 tiles x 128 (tile = 2 kgrp x 8 cols x 8)
//  [8192, 9728)    B dbuf: 2 parities x 12 kgrp x 64 (8 physical cols = batch).
//    K-space (L0, re-permuted weights): k0-47 h1prev | k48-63 x (x read from ring, not stored)
//    K-space (L1):                      k0-47 h1     | k48-95 h2prev
//    k0-47 is SHARED (h1) -> one write, mirror-read serves both layers' MFMA cols.
#define XB 8192
#define STOT (XB + 1536)

typedef short bf8v __attribute__((ext_vector_type(8)));   // 8 x bf16 bits
typedef float f32x4 __attribute__((ext_vector_type(4)));

__device__ __forceinline__ ushort bfb(float f) {
    return __builtin_bit_cast(ushort, (__bf16)f);
}

// sigmoid for the FC epilogue only
__device__ __forceinline__ float sigf(float x) {
    float e = __builtin_amdgcn_exp2f(-1.4426950408889634f * x);
    return __builtin_amdgcn_rcpf(1.0f + e);
}

// LDS-only barrier (no global ops in flight across bodies; refill drains via __syncthreads)
__device__ __forceinline__ void barrier_lds() {
    asm volatile("s_waitcnt lgkmcnt(0)\ns_barrier" ::: "memory");
}

__global__ __launch_bounds__(NTHR)
void lstm_kernel(const float* __restrict__ x,
                 const float* __restrict__ Wih0, const float* __restrict__ Whh0,
                 const float* __restrict__ bih0, const float* __restrict__ bhh0,
                 const float* __restrict__ Wih1, const float* __restrict__ Whh1,
                 const float* __restrict__ bih1, const float* __restrict__ bhh1,
                 const float* __restrict__ fcw, const float* __restrict__ fcb,
                 float* __restrict__ out)
{
    __shared__ alignas(16) ushort S[STOT];
    __shared__ float outl[BT][HH];

    const int tid  = threadIdx.x;
    const int lane = tid & 63;
    const int wave = tid >> 6;
    const int b0   = blockIdx.x * BT;

    const int colq = lane & 15;
    const int quad = lane >> 4;
    const int b    = colq & 7;            // physical batch col
    const bool hi  = (colq >= 8);         // hi: L1 cell; lo: L0 cell (both batch b)
    const int u    = wave * 4 + quad;     // unit owned in C/D: acc[r] = gate r of unit u

    const float L2E = 1.4426950408889634f;

    // ---- loop-invariant LDS addresses (ushort units) ----
    const int fbm = b * 8;                          // mirror col base (cols 8-15 alias 0-7)
    const bool ringlane = (quad >= 2) && !hi;       // r1 lanes that read x from the ring
    const int r0E = XB + quad * 64 + fbm;           // k0-31  (h1, mirror-broadcast)
    const int r0O = r0E + 768;
    const int r2E = XB + (8 + quad) * 64 + fbm;     // k64-95 (h2prev u16-47, mirror)
    const int r2O = r2E + 768;
    const int r1statE = XB + (4 + quad) * 64 + fbm; // k32-63 static part (h1 u32-47 / h2prev u0-15)
    const int r1statO = r1statE + 768;
    const int r1ring0 = (quad - 2) * 64 + colq * 8; // k48-63 = x, ring tile 0 base
    const int inc = ringlane ? 256 : 0;             // ring advance per body pair
    const int kk = hi ? 48 + u : u;                 // write: lo h1 (k=u), hi h2 (k=48+u)
    const int woff = (kk >> 3) * 64 + b * 8 + (kk & 7);
    const int wE = XB + 768 + woff;                 // parity-0 body writes parity 1
    const int wO = XB + woff;

    // ---- C-operand biases: acc reg r = gate type r of unit u ----
    f32x4 bias0, bias1;
#pragma unroll
    for (int r = 0; r < 4; ++r) {
        bias0[r] = bih0[r * 48 + u] + bhh0[r * 48 + u];
        bias1[r] = bih1[r * 48 + u] + bhh1[r * 48 + u];
    }

    // ---- step-invariant weight A-fragments (K re-permuted for L0) ----
    // A-frag: lane holds A[m=colq][k=quad*8+j]; interleaved gate row -> PyTorch gi:
    const int gi = (colq & 3) * 48 + wave * 4 + (colq >> 2);
    bf8v w0k0, w0k1, w1k0, w1k1, w1k2;
    {
        bf8v w;
#pragma unroll
        for (int j = 0; j < 8; ++j) {     // L0 k0-31 -> Whh0 (h1prev)
            int k = quad * 8 + j;
            w[j] = (short)bfb(Whh0[gi * 48 + k]);
        }
        w0k0 = w;
#pragma unroll
        for (int j = 0; j < 8; ++j) {     // L0 k32-63: k<48 Whh0, else Wih0 (x)
            int k = 32 + quad * 8 + j;
            float v = (k < 48) ? Whh0[gi * 48 + k] : Wih0[gi * 16 + (k - 48)];
            w[j] = (short)bfb(v);
        }
        w0k1 = w;
#pragma unroll
        for (int j = 0; j < 8; ++j) {     // L1 k0-31 -> Wih1 (h1)
            int k = quad * 8 + j;
            w[j] = (short)bfb(Wih1[gi * 48 + k]);
        }
        w1k0 = w;
#pragma unroll
        for (int j = 0; j < 8; ++j) {     // L1 k32-63: k<48 Wih1, else Whh1 (h2prev)
            int k = 32 + quad * 8 + j;
            float v = (k < 48) ? Wih1[gi * 48 + k] : Whh1[gi * 48 + (k - 48)];
            w[j] = (short)bfb(v);
        }
        w1k1 = w;
#pragma unroll
        for (int j = 0; j < 8; ++j) {     // L1 k64-95 -> Whh1 (h2prev u16-47)
            int k = 64 + quad * 8 + j;
            w[j] = (short)bfb(Whh1[gi * 48 + (k - 48)]);
        }
        w1k2 = w;
    }

    // ---- init: zero all of S (h1/h2prev start at 0; junk cols bounded) ----
    {
        uint* p = (uint*)S;
        for (int i = tid; i < STOT / 2; i += NTHR) p[i] = 0;
    }
    __syncthreads();

    float c = 0.f;     // lo: c0; hi: c1
    float hv = 0.f;

#define MFMA(A, B, C) __builtin_amdgcn_mfma_f32_16x16x32_bf16(A, B, C, 0, 0, 0)

    // Cell update, rcp-fused (8 transcendentals):
    //   sig(i)*tanh(g) = (1-eg)*rcp((1+ei)(1+eg)),  eg = exp2(-2*L2E*g), ei = exp2(-L2E*i)
    //   cn = rcp(1+ef)*c + above
    //   h  = sig(o)*tanh(cn) = (1-ec)*rcp((1+eo)(1+ec))
    // body t: L0(t) + L1(t-1); 3 ds_read_b128, 5 MFMA, 1 cell, 1 ds_write_b16, 1 barrier
#define BODY(V0A, V1A, V2A, WA, DOL1) { \
        bf8v v0 = *(const bf8v*)&S[V0A]; \
        bf8v v1 = *(const bf8v*)&S[V1A]; \
        bf8v v2 = *(const bf8v*)&S[V2A]; \
        f32x4 acc0 = MFMA(w0k0, v0, bias0); \
        acc0 = MFMA(w0k1, v1, acc0); \
        f32x4 pre; \
        if (DOL1) { \
            f32x4 acc1 = MFMA(w1k0, v0, bias1); \
            acc1 = MFMA(w1k1, v1, acc1); \
            acc1 = MFMA(w1k2, v2, acc1); \
            pre[0] = hi ? acc1[0] : acc0[0]; \
            pre[1] = hi ? acc1[1] : acc0[1]; \
            pre[2] = hi ? acc1[2] : acc0[2]; \
            pre[3] = hi ? acc1[3] : acc0[3]; \
        } else { \
            pre = acc0; \
        } \
        float ei = __builtin_amdgcn_exp2f(-L2E * pre[0]); \
        float ef = __builtin_amdgcn_exp2f(-L2E * pre[1]); \
        float eg = __builtin_amdgcn_exp2f(-2.0f * L2E * pre[2]); \
        float eo = __builtin_amdgcn_exp2f(-L2E * pre[3]); \
        float rig = __builtin_amdgcn_rcpf((1.0f + ei) * (1.0f + eg)); \
        float rf  = __builtin_amdgcn_rcpf(1.0f + ef); \
        float cn = __builtin_fmaf(rf, c, (1.0f - eg) * rig); \
        if (!DOL1) cn = hi ? c : cn;   /* peel: keep L1 state at 0 */ \
        c = cn; \
        float ec = __builtin_amdgcn_exp2f(-2.0f * L2E * cn); \
        float roc = __builtin_amdgcn_rcpf((1.0f + eo) * (1.0f + ec)); \
        hv = (1.0f - ec) * roc; \
        ushort hb = bfb(hv); \
        if (!hi) { S[WA] = hb; } \
        else if (DOL1) { S[WA] = hb; } \
        barrier_lds(); \
    }

    for (int ck = 0; ck < TT / CHUNK; ++ck) {
        // ---- refill x ring for t in [ck*64, ck*64+64): coalesced float4, all waves ----
        for (int i = tid; i < BT * CHUNK * 4; i += NTHR) {   // 2048 float4 rows
            int g  = i & 3;
            int tl = (i >> 2) & (CHUNK - 1);
            int bb = i >> 8;
            const float4 v = *(const float4*)(x +
                ((size_t)(b0 + bb) * TT + (ck * CHUNK + tl)) * DD + g * 4);
            ushort4 s4;
            s4.x = bfb(v.x); s4.y = bfb(v.y); s4.z = bfb(v.z); s4.w = bfb(v.w);
            *(ushort4*)&S[tl * 128 + (g >> 1) * 64 + bb * 8 + (g & 1) * 4] = s4;
        }
        __syncthreads();   // full drain; all global loads are within this refill

        // r1 per-chunk: ring lanes restart at tile 0/1, others static per parity
        int r1E = ringlane ? r1ring0 : r1statE;
        int r1O = ringlane ? (128 + r1ring0) : r1statO;

        int p0 = 0;
        if (ck == 0) {   // peel: first body has no L1 yet
            BODY(r0E, r1E, r2E, wE, false)
            BODY(r0O, r1O, r2O, wO, true)
            r1E += inc; r1O += inc;
            p0 = 1;
        }
        for (int p = p0; p < CHUNK / 2; ++p) {
            BODY(r0E, r1E, r2E, wE, true)
            BODY(r0O, r1O, r2O, wO, true)
            r1E += inc; r1O += inc;
        }
    }

    // ---- post-peel: L1(511) from parity 0 (body 511 wrote h1(511), h2(510) there).
    // Ring lanes' r1 cols are junk for L1 (cols 0-7 unused by acc1) — bounded, in-range.
    {
        int r1E = ringlane ? (r1ring0 + 32 * 256) : r1statE;   // in-bounds junk for ring lanes
        bf8v v0 = *(const bf8v*)&S[r0E];
        bf8v v1 = *(const bf8v*)&S[r1E];
        bf8v v2 = *(const bf8v*)&S[r2E];
        f32x4 acc1 = MFMA(w1k0, v0, bias1);
        acc1 = MFMA(w1k1, v1, acc1);
        acc1 = MFMA(w1k2, v2, acc1);
        float ei = __builtin_amdgcn_exp2f(-L2E * acc1[0]);
        float ef = __builtin_amdgcn_exp2f(-L2E * acc1[1]);
        float eg = __builtin_amdgcn_exp2f(-2.0f * L2E * acc1[2]);
        float eo = __builtin_amdgcn_exp2f(-L2E * acc1[3]);
        float rig = __builtin_amdgcn_rcpf((1.0f + ei) * (1.0f + eg));
        float rf  = __builtin_amdgcn_rcpf(1.0f + ef);
        float cn = __builtin_fmaf(rf, c, (1.0f - eg) * rig);
        float ec = __builtin_amdgcn_exp2f(-2.0f * L2E * cn);
        float roc = __builtin_amdgcn_rcpf((1.0f + eo) * (1.0f + ec));
        hv = (1.0f - ec) * roc;             // valid in hi lanes: h2(511) for (b, u)
    }

    // epilogue: hi lanes own (batch=b, unit=u) of h2(T-1)
    if (hi) outl[b][u] = hv;
    __syncthreads();
    if (tid < BT) {
        float s = fcb[0];
        for (int uu = 0; uu < HH; ++uu) s = __builtin_fmaf(outl[tid][uu], fcw[uu], s);
        out[b0 + tid] = sigf(s);
    }
#undef BODY
#undef MFMA
}

extern "C" void kernel_launch(void* const* d_in, const int* in_sizes, int n_in,
                              void* d_out, int out_size, void* d_ws, size_t ws_size,
                              hipStream_t stream) {
    const float* x    = (const float*)d_in[0];
    const float* Wih0 = (const float*)d_in[1];
    const float* Whh0 = (const float*)d_in[2];
    const float* bih0 = (const float*)d_in[3];
    const float* bhh0 = (const float*)d_in[4];
    const float* Wih1 = (const float*)d_in[5];
    const float* Whh1 = (const float*)d_in[6];
    const float* bih1 = (const float*)d_in[7];
    const float* bhh1 = (const float*)d_in[8];
    const float* fcw  = (const float*)d_in[9];
    const float* fcb  = (const float*)d_in[10];
    lstm_kernel<<<2048 / BT, NTHR, 0, stream>>>(x, Wih0, Whh0, bih0, bhh0,
                                                Wih1, Whh1, bih1, bhh1, fcw, fcb,
                                                (float*)d_out);
}